// Round 11
// baseline (230.919 us; speedup 1.0000x reference)
//
#include <hip/hip_runtime.h>
#include <hip/hip_bf16.h>
#include <cstdint>

// Problem constants
#define Tn 12
#define Nn 512
#define WIN 12
#define DFT 256
#define Pn 16
#define Mrows 24576
#define QSCALE 0.18033688011112042f   // log2(e)/8, folded into q at GEMM epilogue
#define M0F 16.0f                     // fixed softmax reference (scores bounded)

typedef unsigned long long u64;
typedef __attribute__((ext_vector_type(8))) short short8;
typedef __attribute__((ext_vector_type(4))) float f32x4;
typedef __attribute__((address_space(1))) const void* gas1;
typedef __attribute__((address_space(3))) void* las3;

static __device__ __forceinline__ void gld16(const void* g, void* l) {
  __builtin_amdgcn_global_load_lds((gas1)g, (las3)l, 16, 0, 0);
}
static __device__ __forceinline__ short f2bf(float x) {
  __hip_bfloat16 h = __float2bfloat16(x);
  return *reinterpret_cast<short*>(&h);
}
static __device__ __forceinline__ float bf2f(short s) {
  __hip_bfloat16 h;
  *reinterpret_cast<short*>(&h) = s;
  return __bfloat162float(h);
}
static __device__ __forceinline__ f32x4 mfma16(short8 a, short8 b, f32x4 c) {
  return __builtin_amdgcn_mfma_f32_16x16x32_bf16(a, b, c, 0, 0, 0);
}
#if __has_builtin(__builtin_amdgcn_exp2f)
#define EXP2F(x) __builtin_amdgcn_exp2f(x)
#else
#define EXP2F(x) __expf((x) * 0.6931471805599453f)
#endif

// =============== fused prep: all pre-GEMM work in ONE launch ===============
// [0,6144): X|STE cast + fused scalar   [6144,8192): mask bit-pack
// [8192,8640): LDS-tiled weight transpose-cast  [8640,8646): bias concat
// [8646,8662): mem/val
__global__ __launch_bounds__(256) void prep_all(
    const float* __restrict__ X, const float* __restrict__ STE,
    const int* __restrict__ geo, const int* __restrict__ sem,
    const float* __restrict__ PK,
    const float* __restrict__ Wq, const float* __restrict__ bq,
    const float* __restrict__ Wk, const float* __restrict__ bk,
    const float* __restrict__ Wv, const float* __restrict__ bv,
    const float* __restrict__ Wo, const float* __restrict__ Wsc,
    const float* __restrict__ Wpm, const float* __restrict__ Wpv,
    short* __restrict__ Abf, short* __restrict__ Wt3, short* __restrict__ Wot,
    float* __restrict__ bqkv, float* __restrict__ scalar,
    float* __restrict__ mem, float* __restrict__ val,
    u64* __restrict__ gbits, u64* __restrict__ sbits) {
  __shared__ float tl[64][65];   // only used by transpose branch
  const int bid = blockIdx.x, tid = threadIdx.x;
  if (bid < 6144) {                              // X|STE cast + fused scalar
    const int lane = tid & 63, w = tid >> 6;
    const int m = bid * 4 + w;
    const int c8 = lane * 8;
    const float4 x0 = *reinterpret_cast<const float4*>(&X[(size_t)m * 512 + c8]);
    const float4 x1 = *reinterpret_cast<const float4*>(&X[(size_t)m * 512 + c8 + 4]);
    short8 xo;
    xo[0]=f2bf(x0.x); xo[1]=f2bf(x0.y); xo[2]=f2bf(x0.z); xo[3]=f2bf(x0.w);
    xo[4]=f2bf(x1.x); xo[5]=f2bf(x1.y); xo[6]=f2bf(x1.z); xo[7]=f2bf(x1.w);
    *reinterpret_cast<short8*>(&Abf[(size_t)m * 1024 + c8]) = xo;
    const float4 s0 = *reinterpret_cast<const float4*>(&STE[(size_t)m * 512 + c8]);
    const float4 s1 = *reinterpret_cast<const float4*>(&STE[(size_t)m * 512 + c8 + 4]);
    short8 so;
    so[0]=f2bf(s0.x); so[1]=f2bf(s0.y); so[2]=f2bf(s0.z); so[3]=f2bf(s0.w);
    so[4]=f2bf(s1.x); so[5]=f2bf(s1.y); so[6]=f2bf(s1.z); so[7]=f2bf(s1.w);
    *reinterpret_cast<short8*>(&Abf[(size_t)m * 1024 + 512 + c8]) = so;
    const float4 w0 = *reinterpret_cast<const float4*>(&Wsc[c8]);
    const float4 w1 = *reinterpret_cast<const float4*>(&Wsc[c8 + 4]);
    float d = x0.x*w0.x + x0.y*w0.y + x0.z*w0.z + x0.w*w0.w
            + x1.x*w1.x + x1.y*w1.y + x1.z*w1.z + x1.w*w1.w;
#pragma unroll
    for (int off = 32; off; off >>= 1) d += __shfl_xor(d, off);
    if (lane == 0) scalar[m] = d;
  } else if (bid < 8192) {                       // mask bit-pack
    const int pb = bid - 6144;                   // 0..2047
    const int which = pb >> 10, blk = pb & 1023;
    const int lane = tid & 63;
    const int unit = blk * 4 + (tid >> 6);       // 0..4095
    const int n = unit >> 3, seg = unit & 7;
    const int* __restrict__ src = which ? sem : geo;
    u64* __restrict__ dst = which ? sbits : gbits;
    const u64 word = __ballot(src[(size_t)n * 512 + seg * 64 + lane] != 0);
    if (lane == 0) dst[(size_t)n * 8 + seg] = word;
  } else if (bid < 8640) {                       // tiled weight transpose-cast
    const int ti0 = bid - 8192;                  // 0..447
    const float* W;
    short* out;
    int kt, nt, ldk;
    if (ti0 < 384) {
      const int mi = ti0 / 128, ti = ti0 % 128;
      W = (mi == 0) ? Wq : ((mi == 1) ? Wk : Wv);
      out = Wt3 + (size_t)mi * 512 * 1024;
      kt = ti >> 3; nt = ti & 7; ldk = 1024;     // W is 1024x512
    } else {
      const int ti = ti0 - 384;
      W = Wo; out = Wot;
      kt = ti >> 3; nt = ti & 7; ldk = 512;      // W is 512x512
    }
    const int k0 = kt * 64, n0 = nt * 64;
    {
      const int r = tid >> 2, c0 = (tid & 3) * 16;
#pragma unroll
      for (int u = 0; u < 4; ++u) {
        const float4 v = *reinterpret_cast<const float4*>(
            &W[(size_t)(k0 + r) * 512 + n0 + c0 + u * 4]);
        tl[r][c0+u*4+0]=v.x; tl[r][c0+u*4+1]=v.y; tl[r][c0+u*4+2]=v.z; tl[r][c0+u*4+3]=v.w;
      }
    }
    __syncthreads();
    {
      const int nn = tid >> 2, c0 = (tid & 3) * 16;
      short8 o0, o1;
#pragma unroll
      for (int u = 0; u < 8; ++u) o0[u] = f2bf(tl[c0 + u][nn]);
#pragma unroll
      for (int u = 0; u < 8; ++u) o1[u] = f2bf(tl[c0 + 8 + u][nn]);
      *reinterpret_cast<short8*>(&out[(size_t)(n0 + nn) * ldk + k0 + c0]) = o0;
      *reinterpret_cast<short8*>(&out[(size_t)(n0 + nn) * ldk + k0 + c0 + 8]) = o1;
    }
  } else if (bid < 8646) {                       // bias concat
    const int i = (bid - 8640) * 256 + tid;
    bqkv[i] = (i < 512) ? bq[i] : ((i < 1024) ? bk[i - 512] : bv[i - 1024]);
  } else {                                       // mem/val = PK @ Wpm/Wpv
    const int p = bid - 8646, f = tid;
    float m = 0.f, v = 0.f;
#pragma unroll
    for (int i = 0; i < WIN; ++i) {
      const float pk = PK[p * WIN + i];
      m += pk * Wpm[i * DFT + f];
      v += pk * Wpv[i * DFT + f];
    }
    mem[p * DFT + f] = m;
    val[p * DFT + f] = v;
  }
}

// ---------------- 128x128 MFMA GEMM, global_load_lds + XOR swizzle ----------------
// MODE 1: A[M x 1024] -> Cbf [M][1024] (cols<1024, relu bf16; q-cols scaled) and
//         vT[512][M] (cols>=1024, transposed)
// MODE 0: A[M x 512]  -> Cf  [M][512]  relu f32
template <int MODE, int NCB>
__global__ __launch_bounds__(256) void gemm128(
    const short* __restrict__ A, int lda,
    const short* __restrict__ Wt, int Ktot,
    const float* __restrict__ bias,
    short* __restrict__ Cbf, short* __restrict__ vT,
    float* __restrict__ Cf) {
  __shared__ alignas(16) short As[128 * 64];
  __shared__ alignas(16) short Bs[128 * 64];
  const int tid = threadIdx.x, lane = tid & 63, w = tid >> 6;
  const int wm = w >> 1, wn = w & 1, lg = lane >> 4, lc = lane & 15;
  const int L = blockIdx.x;
  const int x = L & 7, j = L >> 3;
  const int rp = x * 24 + j / NCB, cb = j - (j / NCB) * NCB;
  const int row0 = rp * 128, col0 = cb * 128;
  f32x4 acc[4][4];
#pragma unroll
  for (int i = 0; i < 4; ++i)
#pragma unroll
    for (int jj = 0; jj < 4; ++jj) acc[i][jj] = (f32x4){0.f, 0.f, 0.f, 0.f};

  for (int k0 = 0; k0 < Ktot; k0 += 64) {
    __syncthreads();
#pragma unroll
    for (int c = 0; c < 4; ++c) {
      const int slot0 = w * 256 + c * 64;
      const int slot = slot0 + lane;
      const int r = slot >> 3, gs = slot & 7, g = gs ^ (r & 7);
      gld16(&A[(size_t)(row0 + r) * lda + k0 + g * 8], &As[slot0 * 8]);
      gld16(&Wt[(size_t)(col0 + r) * Ktot + k0 + g * 8], &Bs[slot0 * 8]);
    }
    __syncthreads();
#pragma unroll
    for (int kh = 0; kh < 2; ++kh) {
      short8 b[4];
#pragma unroll
      for (int ns = 0; ns < 4; ++ns) {
        const int rb = wn * 64 + ns * 16 + lc;
        b[ns] = *reinterpret_cast<const short8*>(
            &Bs[(rb * 8 + ((kh * 4 + lg) ^ (rb & 7))) * 8]);
      }
#pragma unroll
      for (int ms = 0; ms < 4; ++ms) {
        const int ra = wm * 64 + ms * 16 + lc;
        const short8 a = *reinterpret_cast<const short8*>(
            &As[(ra * 8 + ((kh * 4 + lg) ^ (ra & 7))) * 8]);
#pragma unroll
        for (int ns = 0; ns < 4; ++ns) acc[ms][ns] = mfma16(a, b[ns], acc[ms][ns]);
      }
    }
  }
  // epilogue
#pragma unroll
  for (int ms = 0; ms < 4; ++ms) {
    const int rowb = row0 + wm * 64 + ms * 16 + lg * 4;
#pragma unroll
    for (int ns = 0; ns < 4; ++ns) {
      const int colg = col0 + wn * 64 + ns * 16 + lc;
      const float bv = bias[colg];
      if constexpr (MODE == 0) {
#pragma unroll
        for (int r = 0; r < 4; ++r) {
          float vv = acc[ms][ns][r] + bv;
          Cf[(size_t)(rowb + r) * 512 + colg] = vv > 0.f ? vv : 0.f;
        }
      } else {
        if (colg < 1024) {
          const float sc = (colg < 512) ? QSCALE : 1.f;  // pre-scale q for softmax
#pragma unroll
          for (int r = 0; r < 4; ++r) {
            float vv = acc[ms][ns][r] + bv;
            vv = vv > 0.f ? vv : 0.f;
            Cbf[(size_t)(rowb + r) * 1024 + colg] = f2bf(vv * sc);
          }
        } else {
          short4 t4;
          float vv0 = acc[ms][ns][0] + bv; t4.x = f2bf(vv0 > 0.f ? vv0 : 0.f);
          float vv1 = acc[ms][ns][1] + bv; t4.y = f2bf(vv1 > 0.f ? vv1 : 0.f);
          float vv2 = acc[ms][ns][2] + bv; t4.z = f2bf(vv2 > 0.f ? vv2 : 0.f);
          float vv3 = acc[ms][ns][3] + bv; t4.w = f2bf(vv3 > 0.f ? vv3 : 0.f);
          *reinterpret_cast<short4*>(&vT[(size_t)(colg - 1024) * Mrows + rowb]) = t4;
        }
      }
    }
  }
}

// ---- DFT branch v3: wave-parallel; writes dftq (pre-scaled by QSCALE) ----
// No longer read-modify-writes q; attn adds dftq during its Q-fragment load.
__global__ __launch_bounds__(256) void dft3(
    const float* __restrict__ scalar, const float* __restrict__ Wwq,
    const float* __restrict__ mem, const float* __restrict__ val,
    short* __restrict__ dftq) {
  __shared__ float wwql[12][256];
  __shared__ float meml[16][260];
  __shared__ float vall[16][260];
  __shared__ float qdl[4][256];
  const int tid = threadIdx.x, lane = tid & 63, w = tid >> 6;
  for (int i = tid; i < 3072; i += 256) wwql[0][i] = Wwq[i];   // [12][256] flat
  for (int i = tid; i < 4096; i += 256) {
    meml[i >> 8][i & 255] = mem[i];
    vall[i >> 8][i & 255] = val[i] * QSCALE;   // fold softmax pre-scale
  }
  __syncthreads();
  const int mrow0 = blockIdx.x * 32;
  const int bt = mrow0 >> 9;      // 32 rows stay within one bt (512-aligned)
  const int t = bt % Tn;
  const int p = lane & 15, sg = lane >> 4;
#pragma unroll 1
  for (int it = 0; it < 8; ++it) {
    const int mrow = mrow0 + w * 8 + it;
    const int n = mrow & 511;
    float wl[12];
#pragma unroll
    for (int i = 0; i < 12; ++i) {
      const int ti = t + i - (WIN - 1);
      wl[i] = (ti >= 0) ? scalar[(size_t)(bt + i - (WIN - 1)) * Nn + n] : 0.f;
    }
    float4 qd = {0.f, 0.f, 0.f, 0.f};
#pragma unroll
    for (int i = 0; i < 12; ++i) {
      const float4 wv = *reinterpret_cast<const float4*>(&wwql[i][lane * 4]);
      qd.x += wl[i] * wv.x; qd.y += wl[i] * wv.y;
      qd.z += wl[i] * wv.z; qd.w += wl[i] * wv.w;
    }
    *reinterpret_cast<float4*>(&qdl[w][lane * 4]) = qd;
    asm volatile("s_waitcnt lgkmcnt(0)" ::: "memory");
    float ps = 0.f;
#pragma unroll
    for (int ff = 0; ff < 16; ++ff) {
      const float4 qv = *reinterpret_cast<const float4*>(&qdl[w][sg * 64 + ff * 4]);
      const float4 mv = *reinterpret_cast<const float4*>(&meml[p][sg * 64 + ff * 4]);
      ps += qv.x * mv.x + qv.y * mv.y + qv.z * mv.z + qv.w * mv.w;
    }
    ps += __shfl_xor(ps, 16);
    ps += __shfl_xor(ps, 32);
    const float s = ps * 0.0625f;
    float mx = s;
#pragma unroll
    for (int off = 1; off < 16; off <<= 1) mx = fmaxf(mx, __shfl_xor(mx, off));
    const float e = __expf(s - mx);
    float den = e;
#pragma unroll
    for (int off = 1; off < 16; off <<= 1) den += __shfl_xor(den, off);
    const float a = e / den;
    float4 o = {0.f, 0.f, 0.f, 0.f};
#pragma unroll
    for (int pp = 0; pp < 16; ++pp) {
      const float ap = __shfl(a, pp);
      const float4 vv = *reinterpret_cast<const float4*>(&vall[pp][lane * 4]);
      o.x += ap * vv.x; o.y += ap * vv.y; o.z += ap * vv.z; o.w += ap * vv.w;
    }
    short4 qn;
    qn.x = f2bf(o.x);
    qn.y = f2bf(o.y);
    qn.z = f2bf(o.z);
    qn.w = f2bf(o.w);
    *reinterpret_cast<short4*>(&dftq[(size_t)mrow * 256 + lane * 4]) = qn;
  }
}

// ---- MFMA flash attention v5b: dbuf + fixed-reference softmax + dftq fold ----
#define ASTAGE(B, CH) { \
  _Pragma("unroll") for (int c = 0; c < 2; ++c) { \
    const int slot0 = (w * 2 + c) * 64; \
    const int slot = slot0 + lane; \
    const int r = slot >> 3, gs = slot & 7, gg = gs ^ (r & 7); \
    gld16(&Cm[(rowbase + (CH) * 64 + r) * 1024 + kcol + gg * 8], &Klds[B][slot0 * 8]); \
    gld16(&vT[(size_t)(vrow0 + r) * Mrows + rowbase + (CH) * 64 + gg * 8], \
          &Vlds[B][slot0 * 8]); } }

__global__ __launch_bounds__(256) void attn5(
    const short* __restrict__ Cm, const short* __restrict__ vT,
    const short* __restrict__ dftq,
    const u64* __restrict__ gbits, const u64* __restrict__ sbits,
    short* __restrict__ merged) {
  const int L = blockIdx.x;            // 0..1535
  const int x = L & 7, j = L >> 3;     // j 0..191
  const int g = x * 48 + (j >> 2);     // same (head,bt) -> same XCD
  const int qt = j & 3;
  const int head = g & 7, bt = g >> 3;
  const u64* __restrict__ bits = (head < 4) ? gbits : sbits;
  const int tid = threadIdx.x, lane = tid & 63, w = tid >> 6;
  const int lg = lane >> 4, qc = lane & 15;
  const size_t rowbase = (size_t)bt * 512;
  const int n0 = qt * 128;
  const int qcol = head * 64, kcol = 512 + head * 64, vrow0 = head * 64;

  __shared__ alignas(16) short Klds[2][4096];
  __shared__ alignas(16) short Vlds[2][4096];
  __shared__ alignas(16) short Plds[4][2][16][72];

  short8 qf[2][2];
  int qrow[2];
#pragma unroll
  for (int qs = 0; qs < 2; ++qs) {
    qrow[qs] = n0 + w * 32 + qs * 16 + qc;
    qf[qs][0] = *reinterpret_cast<const short8*>(
        &Cm[(rowbase + qrow[qs]) * 1024 + qcol + lg * 8]);
    qf[qs][1] = *reinterpret_cast<const short8*>(
        &Cm[(rowbase + qrow[qs]) * 1024 + qcol + 32 + lg * 8]);
  }
  if (head < 4) {   // geo heads: fold DFT branch contribution into q fragments
#pragma unroll
    for (int qs = 0; qs < 2; ++qs)
#pragma unroll
      for (int h = 0; h < 2; ++h) {
        const short8 d8 = *reinterpret_cast<const short8*>(
            &dftq[(rowbase + qrow[qs]) * 256 + head * 64 + h * 32 + lg * 8]);
        short8 q8 = qf[qs][h];
#pragma unroll
        for (int jj = 0; jj < 8; ++jj)
          q8[jj] = f2bf(bf2f(q8[jj]) + bf2f(d8[jj]));
        qf[qs][h] = q8;
      }
  }

  float l_run[2] = {0.f, 0.f};
  f32x4 o[2][4];
#pragma unroll
  for (int qs = 0; qs < 2; ++qs)
#pragma unroll
    for (int i = 0; i < 4; ++i) o[qs][i] = (f32x4){0.f, 0.f, 0.f, 0.f};
  const f32x4 minit = (f32x4){-M0F, -M0F, -M0F, -M0F};

  ASTAGE(0, 0);
  u64 mw0 = bits[(size_t)(n0 + w * 32 + qc) * 8];
  u64 mw1 = bits[(size_t)(n0 + w * 32 + 16 + qc) * 8];
  asm volatile("s_waitcnt vmcnt(0)" ::: "memory");
  __syncthreads();

  int cur = 0;
#pragma unroll 1
  for (int ch = 0; ch < 8; ++ch) {
    if (ch < 7) ASTAGE(cur ^ 1, ch + 1);            // prefetch next chunk
    u64 nmw0 = 0, nmw1 = 0;
    if (ch < 7) {                                    // prefetch next masks
      nmw0 = bits[(size_t)(n0 + w * 32 + qc) * 8 + ch + 1];
      nmw1 = bits[(size_t)(n0 + w * 32 + 16 + qc) * 8 + ch + 1];
    }
    // S^T = K . Q^T - 16 (scores pre-scaled by log2e/8 via q), exp2 fused
    float csum0 = 0.f, csum1 = 0.f;
#pragma unroll
    for (int s = 0; s < 4; ++s) {
      const int rk = s * 16 + qc;
      const short8 a0 = *reinterpret_cast<const short8*>(
          &Klds[cur][(rk * 8 + (lg ^ (rk & 7))) * 8]);
      const short8 a1 = *reinterpret_cast<const short8*>(
          &Klds[cur][(rk * 8 + ((4 + lg) ^ (rk & 7))) * 8]);
      f32x4 sa0 = minit, sa1 = minit;
      __builtin_amdgcn_s_setprio(1);
      sa0 = mfma16(a0, qf[0][0], sa0);
      sa0 = mfma16(a1, qf[0][1], sa0);
      sa1 = mfma16(a0, qf[1][0], sa1);
      sa1 = mfma16(a1, qf[1][1], sa1);
      __builtin_amdgcn_s_setprio(0);
      short4 p40, p41;
#pragma unroll
      for (int r = 0; r < 4; ++r) {
        const int kb = s * 16 + lg * 4 + r;
        const float pv0 = EXP2F(((mw0 >> kb) & 1ull) ? sa0[r] : -1e30f);
        const float pv1 = EXP2F(((mw1 >> kb) & 1ull) ? sa1[r] : -1e30f);
        csum0 += pv0; csum1 += pv1;
        ((short*)&p40)[r] = f2bf(pv0);
        ((short*)&p41)[r] = f2bf(pv1);
      }
      *reinterpret_cast<short4*>(&Plds[w][0][qc][s * 16 + lg * 4]) = p40;
      *reinterpret_cast<short4*>(&Plds[w][1][qc][s * 16 + lg * 4]) = p41;
    }
    csum0 += __shfl_xor(csum0, 16);
    csum0 += __shfl_xor(csum0, 32);
    csum1 += __shfl_xor(csum1, 16);
    csum1 += __shfl_xor(csum1, 32);
    l_run[0] += csum0;
    l_run[1] += csum1;

    // O^T += V^T . P^T, V fragments shared across q-subtiles
#pragma unroll
    for (int kh = 0; kh < 2; ++kh) {
      const short8 pb0 = *reinterpret_cast<const short8*>(
          &Plds[w][0][qc][kh * 32 + lg * 8]);
      const short8 pb1 = *reinterpret_cast<const short8*>(
          &Plds[w][1][qc][kh * 32 + lg * 8]);
      __builtin_amdgcn_s_setprio(1);
#pragma unroll
      for (int ds = 0; ds < 4; ++ds) {
        const int rd = ds * 16 + qc;
        const short8 va = *reinterpret_cast<const short8*>(
            &Vlds[cur][(rd * 8 + ((kh * 4 + lg) ^ (rd & 7))) * 8]);
        o[0][ds] = mfma16(va, pb0, o[0][ds]);
        o[1][ds] = mfma16(va, pb1, o[1][ds]);
      }
      __builtin_amdgcn_s_setprio(0);
    }
    asm volatile("s_waitcnt vmcnt(0)" ::: "memory");   // next chunk landed
    __syncthreads();                                    // all waves done with cur
    cur ^= 1;
    mw0 = nmw0; mw1 = nmw1;
  }
#pragma unroll
  for (int qs = 0; qs < 2; ++qs) {
    const float inv = l_run[qs] > 0.f ? 1.f / l_run[qs] : 0.f;
#pragma unroll
    for (int ds = 0; ds < 4; ++ds) {
      short4 t4;
      t4.x = f2bf(o[qs][ds][0] * inv);
      t4.y = f2bf(o[qs][ds][1] * inv);
      t4.z = f2bf(o[qs][ds][2] * inv);
      t4.w = f2bf(o[qs][ds][3] * inv);
      *reinterpret_cast<short4*>(
          &merged[(rowbase + qrow[qs]) * 512 + head * 64 + ds * 16 + lg * 4]) = t4;
    }
  }
}

// ---------------- launch ----------------
extern "C" void kernel_launch(void* const* d_in, const int* in_sizes, int n_in,
                              void* d_out, int out_size, void* d_ws, size_t ws_size,
                              hipStream_t stream) {
  const float* X        = (const float*)d_in[0];
  const float* STE      = (const float*)d_in[1];
  const int*   geo_mask = (const int*)d_in[2];
  const int*   sem_mask = (const int*)d_in[3];
  const float* PK       = (const float*)d_in[4];
  const float* Wq       = (const float*)d_in[5];
  const float* bq       = (const float*)d_in[6];
  const float* Wk       = (const float*)d_in[7];
  const float* bk       = (const float*)d_in[8];
  const float* Wv       = (const float*)d_in[9];
  const float* bv       = (const float*)d_in[10];
  const float* Wo       = (const float*)d_in[11];
  const float* bo       = (const float*)d_in[12];
  const float* Wsc      = (const float*)d_in[13];
  const float* Wwq      = (const float*)d_in[14];
  const float* Wpm      = (const float*)d_in[15];
  const float* Wpv      = (const float*)d_in[16];
  float* out = (float*)d_out;

  char* wsb = (char*)d_ws;
  short* Abf     = (short*)(wsb);                    // 24576x1024 bf16
  short* mergedb = (short*)(wsb);                    // aliases Abf (dead after QKV)
  short* Cm      = (short*)(wsb + 50331648);         // 24576x1024 bf16: q|k
  short* vT      = (short*)(wsb + 100663296);        // 512x24576 bf16
  short* Wt3     = (short*)(wsb + 125829120);        // 1536x1024 bf16
  short* Wot     = (short*)(wsb + 128974848);        // 512x512 bf16
  float* bqkv    = (float*)(wsb + 129499136);        // 1536 f32
  float* scalar  = (float*)(wsb + 129505280);        // 24576 f32
  float* mem     = (float*)(wsb + 129603584);
  float* val     = (float*)(wsb + 129619968);
  u64*   gbits   = (u64*)  (wsb + 129636352);
  u64*   sbits   = (u64*)  (wsb + 129669120);
  short* dftq    = (short*)(wsb + 129701888);        // 24576x256 bf16 (12.5MB)

  // all prep in one launch (cast+scalar | masks | tiled W transpose | bias | mem/val)
  prep_all<<<dim3(8662), dim3(256), 0, stream>>>(
      X, STE, geo_mask, sem_mask, PK, Wq, bq, Wk, bk, Wv, bv, Wo, Wsc, Wpm, Wpv,
      Abf, Wt3, Wot, bqkv, scalar, mem, val, gbits, sbits);

  // DFT branch -> dftq (independent of GEMM now)
  dft3<<<dim3(Mrows / 32), dim3(256), 0, stream>>>(scalar, Wwq, mem, val, dftq);

  // merged QKV GEMM: M=24576, K=1024, N=1536 (writes Cm q|k + vT transposed)
  gemm128<1, 12><<<dim3(2304), dim3(256), 0, stream>>>(
      Abf, 1024, Wt3, 1024, bqkv, Cm, vT, nullptr);

  // flash attention (fixed-reference softmax; folds dftq into geo-head q)
  attn5<<<dim3(1536), dim3(256), 0, stream>>>(Cm, vT, dftq, gbits, sbits, mergedb);

  // output FC: M=24576, K=512, N=512, f32 out
  gemm128<0, 4><<<dim3(768), dim3(256), 0, stream>>>(
      mergedb, 512, Wot, 512, bo, nullptr, nullptr, out);
}

// Round 12
// 226.758 us; speedup vs baseline: 1.0184x; 1.0184x over previous
//
#include <hip/hip_runtime.h>
#include <hip/hip_bf16.h>
#include <cstdint>

// Problem constants
#define Tn 12
#define Nn 512
#define WIN 12
#define DFT 256
#define Pn 16
#define Mrows 24576
#define QSCALE 0.18033688011112042f   // log2(e)/8, folded into q at GEMM epilogue
#define M0F 16.0f                     // fixed softmax reference (scores bounded)

typedef unsigned long long u64;
typedef __attribute__((ext_vector_type(8))) short short8;
typedef __attribute__((ext_vector_type(4))) float f32x4;
typedef __attribute__((address_space(1))) const void* gas1;
typedef __attribute__((address_space(3))) void* las3;

static __device__ __forceinline__ void gld16(const void* g, void* l) {
  __builtin_amdgcn_global_load_lds((gas1)g, (las3)l, 16, 0, 0);
}
static __device__ __forceinline__ short f2bf(float x) {
  __hip_bfloat16 h = __float2bfloat16(x);
  return *reinterpret_cast<short*>(&h);
}
static __device__ __forceinline__ float bf2f(short s) {
  __hip_bfloat16 h;
  *reinterpret_cast<short*>(&h) = s;
  return __bfloat162float(h);
}
static __device__ __forceinline__ f32x4 mfma16(short8 a, short8 b, f32x4 c) {
  return __builtin_amdgcn_mfma_f32_16x16x32_bf16(a, b, c, 0, 0, 0);
}
#if __has_builtin(__builtin_amdgcn_exp2f)
#define EXP2F(x) __builtin_amdgcn_exp2f(x)
#else
#define EXP2F(x) __expf((x) * 0.6931471805599453f)
#endif

// =============== fused prep: all pre-GEMM work in ONE launch ===============
// [0,6144): X|STE cast + fused scalar   [6144,8192): mask bit-pack
// [8192,8640): LDS-tiled weight transpose-cast  [8640,8646): bias concat
// [8646,8662): mem/val
__global__ __launch_bounds__(256) void prep_all(
    const float* __restrict__ X, const float* __restrict__ STE,
    const int* __restrict__ geo, const int* __restrict__ sem,
    const float* __restrict__ PK,
    const float* __restrict__ Wq, const float* __restrict__ bq,
    const float* __restrict__ Wk, const float* __restrict__ bk,
    const float* __restrict__ Wv, const float* __restrict__ bv,
    const float* __restrict__ Wo, const float* __restrict__ Wsc,
    const float* __restrict__ Wpm, const float* __restrict__ Wpv,
    short* __restrict__ Abf, short* __restrict__ Wt3, short* __restrict__ Wot,
    float* __restrict__ bqkv, float* __restrict__ scalar,
    float* __restrict__ mem, float* __restrict__ val,
    u64* __restrict__ gbits, u64* __restrict__ sbits) {
  __shared__ float tl[64][65];   // only used by transpose branch
  const int bid = blockIdx.x, tid = threadIdx.x;
  if (bid < 6144) {                              // X|STE cast + fused scalar
    const int lane = tid & 63, w = tid >> 6;
    const int m = bid * 4 + w;
    const int c8 = lane * 8;
    const float4 x0 = *reinterpret_cast<const float4*>(&X[(size_t)m * 512 + c8]);
    const float4 x1 = *reinterpret_cast<const float4*>(&X[(size_t)m * 512 + c8 + 4]);
    short8 xo;
    xo[0]=f2bf(x0.x); xo[1]=f2bf(x0.y); xo[2]=f2bf(x0.z); xo[3]=f2bf(x0.w);
    xo[4]=f2bf(x1.x); xo[5]=f2bf(x1.y); xo[6]=f2bf(x1.z); xo[7]=f2bf(x1.w);
    *reinterpret_cast<short8*>(&Abf[(size_t)m * 1024 + c8]) = xo;
    const float4 s0 = *reinterpret_cast<const float4*>(&STE[(size_t)m * 512 + c8]);
    const float4 s1 = *reinterpret_cast<const float4*>(&STE[(size_t)m * 512 + c8 + 4]);
    short8 so;
    so[0]=f2bf(s0.x); so[1]=f2bf(s0.y); so[2]=f2bf(s0.z); so[3]=f2bf(s0.w);
    so[4]=f2bf(s1.x); so[5]=f2bf(s1.y); so[6]=f2bf(s1.z); so[7]=f2bf(s1.w);
    *reinterpret_cast<short8*>(&Abf[(size_t)m * 1024 + 512 + c8]) = so;
    const float4 w0 = *reinterpret_cast<const float4*>(&Wsc[c8]);
    const float4 w1 = *reinterpret_cast<const float4*>(&Wsc[c8 + 4]);
    float d = x0.x*w0.x + x0.y*w0.y + x0.z*w0.z + x0.w*w0.w
            + x1.x*w1.x + x1.y*w1.y + x1.z*w1.z + x1.w*w1.w;
#pragma unroll
    for (int off = 32; off; off >>= 1) d += __shfl_xor(d, off);
    if (lane == 0) scalar[m] = d;
  } else if (bid < 8192) {                       // mask bit-pack
    const int pb = bid - 6144;                   // 0..2047
    const int which = pb >> 10, blk = pb & 1023;
    const int lane = tid & 63;
    const int unit = blk * 4 + (tid >> 6);       // 0..4095
    const int n = unit >> 3, seg = unit & 7;
    const int* __restrict__ src = which ? sem : geo;
    u64* __restrict__ dst = which ? sbits : gbits;
    const u64 word = __ballot(src[(size_t)n * 512 + seg * 64 + lane] != 0);
    if (lane == 0) dst[(size_t)n * 8 + seg] = word;
  } else if (bid < 8640) {                       // tiled weight transpose-cast
    const int ti0 = bid - 8192;                  // 0..447
    const float* W;
    short* out;
    int kt, nt, ldk;
    if (ti0 < 384) {
      const int mi = ti0 / 128, ti = ti0 % 128;
      W = (mi == 0) ? Wq : ((mi == 1) ? Wk : Wv);
      out = Wt3 + (size_t)mi * 512 * 1024;
      kt = ti >> 3; nt = ti & 7; ldk = 1024;     // W is 1024x512
    } else {
      const int ti = ti0 - 384;
      W = Wo; out = Wot;
      kt = ti >> 3; nt = ti & 7; ldk = 512;      // W is 512x512
    }
    const int k0 = kt * 64, n0 = nt * 64;
    {
      const int r = tid >> 2, c0 = (tid & 3) * 16;
#pragma unroll
      for (int u = 0; u < 4; ++u) {
        const float4 v = *reinterpret_cast<const float4*>(
            &W[(size_t)(k0 + r) * 512 + n0 + c0 + u * 4]);
        tl[r][c0+u*4+0]=v.x; tl[r][c0+u*4+1]=v.y; tl[r][c0+u*4+2]=v.z; tl[r][c0+u*4+3]=v.w;
      }
    }
    __syncthreads();
    {
      const int nn = tid >> 2, c0 = (tid & 3) * 16;
      short8 o0, o1;
#pragma unroll
      for (int u = 0; u < 8; ++u) o0[u] = f2bf(tl[c0 + u][nn]);
#pragma unroll
      for (int u = 0; u < 8; ++u) o1[u] = f2bf(tl[c0 + 8 + u][nn]);
      *reinterpret_cast<short8*>(&out[(size_t)(n0 + nn) * ldk + k0 + c0]) = o0;
      *reinterpret_cast<short8*>(&out[(size_t)(n0 + nn) * ldk + k0 + c0 + 8]) = o1;
    }
  } else if (bid < 8646) {                       // bias concat
    const int i = (bid - 8640) * 256 + tid;
    bqkv[i] = (i < 512) ? bq[i] : ((i < 1024) ? bk[i - 512] : bv[i - 1024]);
  } else {                                       // mem/val = PK @ Wpm/Wpv
    const int p = bid - 8646, f = tid;
    float m = 0.f, v = 0.f;
#pragma unroll
    for (int i = 0; i < WIN; ++i) {
      const float pk = PK[p * WIN + i];
      m += pk * Wpm[i * DFT + f];
      v += pk * Wpv[i * DFT + f];
    }
    mem[p * DFT + f] = m;
    val[p * DFT + f] = v;
  }
}

// ---------------- 128x128 MFMA GEMM, global_load_lds + XOR swizzle ----------------
// MODE 1: A[M x 1024] -> Cbf [M][1024] (cols<1024, relu bf16; q-cols scaled) and
//         vT[512][M] (cols>=1024, transposed)
// MODE 0: A[M x 512]  -> Cf  [M][512]  relu f32
template <int MODE, int NCB>
__global__ __launch_bounds__(256) void gemm128(
    const short* __restrict__ A, int lda,
    const short* __restrict__ Wt, int Ktot,
    const float* __restrict__ bias,
    short* __restrict__ Cbf, short* __restrict__ vT,
    float* __restrict__ Cf) {
  __shared__ alignas(16) short As[128 * 64];
  __shared__ alignas(16) short Bs[128 * 64];
  const int tid = threadIdx.x, lane = tid & 63, w = tid >> 6;
  const int wm = w >> 1, wn = w & 1, lg = lane >> 4, lc = lane & 15;
  const int L = blockIdx.x;
  const int x = L & 7, j = L >> 3;
  const int rp = x * 24 + j / NCB, cb = j - (j / NCB) * NCB;
  const int row0 = rp * 128, col0 = cb * 128;
  f32x4 acc[4][4];
#pragma unroll
  for (int i = 0; i < 4; ++i)
#pragma unroll
    for (int jj = 0; jj < 4; ++jj) acc[i][jj] = (f32x4){0.f, 0.f, 0.f, 0.f};

  for (int k0 = 0; k0 < Ktot; k0 += 64) {
    __syncthreads();
#pragma unroll
    for (int c = 0; c < 4; ++c) {
      const int slot0 = w * 256 + c * 64;
      const int slot = slot0 + lane;
      const int r = slot >> 3, gs = slot & 7, g = gs ^ (r & 7);
      gld16(&A[(size_t)(row0 + r) * lda + k0 + g * 8], &As[slot0 * 8]);
      gld16(&Wt[(size_t)(col0 + r) * Ktot + k0 + g * 8], &Bs[slot0 * 8]);
    }
    __syncthreads();
#pragma unroll
    for (int kh = 0; kh < 2; ++kh) {
      short8 b[4];
#pragma unroll
      for (int ns = 0; ns < 4; ++ns) {
        const int rb = wn * 64 + ns * 16 + lc;
        b[ns] = *reinterpret_cast<const short8*>(
            &Bs[(rb * 8 + ((kh * 4 + lg) ^ (rb & 7))) * 8]);
      }
#pragma unroll
      for (int ms = 0; ms < 4; ++ms) {
        const int ra = wm * 64 + ms * 16 + lc;
        const short8 a = *reinterpret_cast<const short8*>(
            &As[(ra * 8 + ((kh * 4 + lg) ^ (ra & 7))) * 8]);
#pragma unroll
        for (int ns = 0; ns < 4; ++ns) acc[ms][ns] = mfma16(a, b[ns], acc[ms][ns]);
      }
    }
  }
  // epilogue
#pragma unroll
  for (int ms = 0; ms < 4; ++ms) {
    const int rowb = row0 + wm * 64 + ms * 16 + lg * 4;
#pragma unroll
    for (int ns = 0; ns < 4; ++ns) {
      const int colg = col0 + wn * 64 + ns * 16 + lc;
      const float bv = bias[colg];
      if constexpr (MODE == 0) {
#pragma unroll
        for (int r = 0; r < 4; ++r) {
          float vv = acc[ms][ns][r] + bv;
          Cf[(size_t)(rowb + r) * 512 + colg] = vv > 0.f ? vv : 0.f;
        }
      } else {
        if (colg < 1024) {
          const float sc = (colg < 512) ? QSCALE : 1.f;  // pre-scale q for softmax
#pragma unroll
          for (int r = 0; r < 4; ++r) {
            float vv = acc[ms][ns][r] + bv;
            vv = vv > 0.f ? vv : 0.f;
            Cbf[(size_t)(rowb + r) * 1024 + colg] = f2bf(vv * sc);
          }
        } else {
          short4 t4;
          float vv0 = acc[ms][ns][0] + bv; t4.x = f2bf(vv0 > 0.f ? vv0 : 0.f);
          float vv1 = acc[ms][ns][1] + bv; t4.y = f2bf(vv1 > 0.f ? vv1 : 0.f);
          float vv2 = acc[ms][ns][2] + bv; t4.z = f2bf(vv2 > 0.f ? vv2 : 0.f);
          float vv3 = acc[ms][ns][3] + bv; t4.w = f2bf(vv3 > 0.f ? vv3 : 0.f);
          *reinterpret_cast<short4*>(&vT[(size_t)(colg - 1024) * Mrows + rowb]) = t4;
        }
      }
    }
  }
}

// ---- DFT branch v2: wave-parallel; output pre-scaled by QSCALE via vall ----
__global__ __launch_bounds__(256) void dft2(
    const float* __restrict__ scalar, const float* __restrict__ Wwq,
    const float* __restrict__ mem, const float* __restrict__ val,
    short* __restrict__ q) {
  __shared__ float wwql[12][256];
  __shared__ float meml[16][260];
  __shared__ float vall[16][260];
  __shared__ float qdl[4][256];
  const int tid = threadIdx.x, lane = tid & 63, w = tid >> 6;
  for (int i = tid; i < 3072; i += 256) wwql[0][i] = Wwq[i];   // [12][256] flat
  for (int i = tid; i < 4096; i += 256) {
    meml[i >> 8][i & 255] = mem[i];
    vall[i >> 8][i & 255] = val[i] * QSCALE;   // fold softmax pre-scale
  }
  __syncthreads();
  const int mrow0 = blockIdx.x * 32;
  const int bt = mrow0 >> 9;      // 32 rows stay within one bt (512-aligned)
  const int t = bt % Tn;
  const int p = lane & 15, sg = lane >> 4;
#pragma unroll 1
  for (int it = 0; it < 8; ++it) {
    const int mrow = mrow0 + w * 8 + it;
    const int n = mrow & 511;
    float wl[12];
#pragma unroll
    for (int i = 0; i < 12; ++i) {
      const int ti = t + i - (WIN - 1);
      wl[i] = (ti >= 0) ? scalar[(size_t)(bt + i - (WIN - 1)) * Nn + n] : 0.f;
    }
    float4 qd = {0.f, 0.f, 0.f, 0.f};
#pragma unroll
    for (int i = 0; i < 12; ++i) {
      const float4 wv = *reinterpret_cast<const float4*>(&wwql[i][lane * 4]);
      qd.x += wl[i] * wv.x; qd.y += wl[i] * wv.y;
      qd.z += wl[i] * wv.z; qd.w += wl[i] * wv.w;
    }
    *reinterpret_cast<float4*>(&qdl[w][lane * 4]) = qd;
    asm volatile("s_waitcnt lgkmcnt(0)" ::: "memory");
    float ps = 0.f;
#pragma unroll
    for (int ff = 0; ff < 16; ++ff) {
      const float4 qv = *reinterpret_cast<const float4*>(&qdl[w][sg * 64 + ff * 4]);
      const float4 mv = *reinterpret_cast<const float4*>(&meml[p][sg * 64 + ff * 4]);
      ps += qv.x * mv.x + qv.y * mv.y + qv.z * mv.z + qv.w * mv.w;
    }
    ps += __shfl_xor(ps, 16);
    ps += __shfl_xor(ps, 32);
    const float s = ps * 0.0625f;
    float mx = s;
#pragma unroll
    for (int off = 1; off < 16; off <<= 1) mx = fmaxf(mx, __shfl_xor(mx, off));
    const float e = __expf(s - mx);
    float den = e;
#pragma unroll
    for (int off = 1; off < 16; off <<= 1) den += __shfl_xor(den, off);
    const float a = e / den;
    float4 o = {0.f, 0.f, 0.f, 0.f};
#pragma unroll
    for (int pp = 0; pp < 16; ++pp) {
      const float ap = __shfl(a, pp);
      const float4 vv = *reinterpret_cast<const float4*>(&vall[pp][lane * 4]);
      o.x += ap * vv.x; o.y += ap * vv.y; o.z += ap * vv.z; o.w += ap * vv.w;
    }
    const size_t qi = (size_t)mrow * 1024 + lane * 4;
    short4 qo = *reinterpret_cast<const short4*>(&q[qi]);
    short4 qn;
    qn.x = f2bf(bf2f(qo.x) + o.x);
    qn.y = f2bf(bf2f(qo.y) + o.y);
    qn.z = f2bf(bf2f(qo.z) + o.z);
    qn.w = f2bf(bf2f(qo.w) + o.w);
    *reinterpret_cast<short4*>(&q[qi]) = qn;
  }
}

// ---- MFMA flash attention v5: dbuf + fixed-reference softmax (no max pass) ----
// Scores s = log2e/8 * <q,k> - 16 (via MFMA C-init) are bounded; P = exp2(s),
// normalized by running sum. No max tracking, no rescale, no defer logic.
#define ASTAGE(B, CH) { \
  _Pragma("unroll") for (int c = 0; c < 2; ++c) { \
    const int slot0 = (w * 2 + c) * 64; \
    const int slot = slot0 + lane; \
    const int r = slot >> 3, gs = slot & 7, gg = gs ^ (r & 7); \
    gld16(&Cm[(rowbase + (CH) * 64 + r) * 1024 + kcol + gg * 8], &Klds[B][slot0 * 8]); \
    gld16(&vT[(size_t)(vrow0 + r) * Mrows + rowbase + (CH) * 64 + gg * 8], \
          &Vlds[B][slot0 * 8]); } }

__global__ __launch_bounds__(256) void attn5(
    const short* __restrict__ Cm, const short* __restrict__ vT,
    const u64* __restrict__ gbits, const u64* __restrict__ sbits,
    short* __restrict__ merged) {
  const int L = blockIdx.x;            // 0..1535
  const int x = L & 7, j = L >> 3;     // j 0..191
  const int g = x * 48 + (j >> 2);     // same (head,bt) -> same XCD
  const int qt = j & 3;
  const int head = g & 7, bt = g >> 3;
  const u64* __restrict__ bits = (head < 4) ? gbits : sbits;
  const int tid = threadIdx.x, lane = tid & 63, w = tid >> 6;
  const int lg = lane >> 4, qc = lane & 15;
  const size_t rowbase = (size_t)bt * 512;
  const int n0 = qt * 128;
  const int qcol = head * 64, kcol = 512 + head * 64, vrow0 = head * 64;

  __shared__ alignas(16) short Klds[2][4096];
  __shared__ alignas(16) short Vlds[2][4096];
  __shared__ alignas(16) short Plds[4][2][16][72];

  short8 qf[2][2];
  int qrow[2];
#pragma unroll
  for (int qs = 0; qs < 2; ++qs) {
    qrow[qs] = n0 + w * 32 + qs * 16 + qc;
    qf[qs][0] = *reinterpret_cast<const short8*>(
        &Cm[(rowbase + qrow[qs]) * 1024 + qcol + lg * 8]);
    qf[qs][1] = *reinterpret_cast<const short8*>(
        &Cm[(rowbase + qrow[qs]) * 1024 + qcol + 32 + lg * 8]);
  }

  float l_run[2] = {0.f, 0.f};
  f32x4 o[2][4];
#pragma unroll
  for (int qs = 0; qs < 2; ++qs)
#pragma unroll
    for (int i = 0; i < 4; ++i) o[qs][i] = (f32x4){0.f, 0.f, 0.f, 0.f};
  const f32x4 minit = (f32x4){-M0F, -M0F, -M0F, -M0F};

  ASTAGE(0, 0);
  u64 mw0 = bits[(size_t)(n0 + w * 32 + qc) * 8];
  u64 mw1 = bits[(size_t)(n0 + w * 32 + 16 + qc) * 8];
  asm volatile("s_waitcnt vmcnt(0)" ::: "memory");
  __syncthreads();

  int cur = 0;
#pragma unroll 1
  for (int ch = 0; ch < 8; ++ch) {
    if (ch < 7) ASTAGE(cur ^ 1, ch + 1);            // prefetch next chunk
    u64 nmw0 = 0, nmw1 = 0;
    if (ch < 7) {                                    // prefetch next masks
      nmw0 = bits[(size_t)(n0 + w * 32 + qc) * 8 + ch + 1];
      nmw1 = bits[(size_t)(n0 + w * 32 + 16 + qc) * 8 + ch + 1];
    }
    // S^T = K . Q^T - 16 (scores pre-scaled by log2e/8 via q), exp2 fused
    float csum0 = 0.f, csum1 = 0.f;
#pragma unroll
    for (int s = 0; s < 4; ++s) {
      const int rk = s * 16 + qc;
      const short8 a0 = *reinterpret_cast<const short8*>(
          &Klds[cur][(rk * 8 + (lg ^ (rk & 7))) * 8]);
      const short8 a1 = *reinterpret_cast<const short8*>(
          &Klds[cur][(rk * 8 + ((4 + lg) ^ (rk & 7))) * 8]);
      f32x4 sa0 = minit, sa1 = minit;
      __builtin_amdgcn_s_setprio(1);
      sa0 = mfma16(a0, qf[0][0], sa0);
      sa0 = mfma16(a1, qf[0][1], sa0);
      sa1 = mfma16(a0, qf[1][0], sa1);
      sa1 = mfma16(a1, qf[1][1], sa1);
      __builtin_amdgcn_s_setprio(0);
      short4 p40, p41;
#pragma unroll
      for (int r = 0; r < 4; ++r) {
        const int kb = s * 16 + lg * 4 + r;
        const float pv0 = EXP2F(((mw0 >> kb) & 1ull) ? sa0[r] : -1e30f);
        const float pv1 = EXP2F(((mw1 >> kb) & 1ull) ? sa1[r] : -1e30f);
        csum0 += pv0; csum1 += pv1;
        ((short*)&p40)[r] = f2bf(pv0);
        ((short*)&p41)[r] = f2bf(pv1);
      }
      *reinterpret_cast<short4*>(&Plds[w][0][qc][s * 16 + lg * 4]) = p40;
      *reinterpret_cast<short4*>(&Plds[w][1][qc][s * 16 + lg * 4]) = p41;
    }
    csum0 += __shfl_xor(csum0, 16);
    csum0 += __shfl_xor(csum0, 32);
    csum1 += __shfl_xor(csum1, 16);
    csum1 += __shfl_xor(csum1, 32);
    l_run[0] += csum0;
    l_run[1] += csum1;

    // O^T += V^T . P^T, V fragments shared across q-subtiles
#pragma unroll
    for (int kh = 0; kh < 2; ++kh) {
      const short8 pb0 = *reinterpret_cast<const short8*>(
          &Plds[w][0][qc][kh * 32 + lg * 8]);
      const short8 pb1 = *reinterpret_cast<const short8*>(
          &Plds[w][1][qc][kh * 32 + lg * 8]);
      __builtin_amdgcn_s_setprio(1);
#pragma unroll
      for (int ds = 0; ds < 4; ++ds) {
        const int rd = ds * 16 + qc;
        const short8 va = *reinterpret_cast<const short8*>(
            &Vlds[cur][(rd * 8 + ((kh * 4 + lg) ^ (rd & 7))) * 8]);
        o[0][ds] = mfma16(va, pb0, o[0][ds]);
        o[1][ds] = mfma16(va, pb1, o[1][ds]);
      }
      __builtin_amdgcn_s_setprio(0);
    }
    asm volatile("s_waitcnt vmcnt(0)" ::: "memory");   // next chunk landed
    __syncthreads();                                    // all waves done with cur
    cur ^= 1;
    mw0 = nmw0; mw1 = nmw1;
  }
#pragma unroll
  for (int qs = 0; qs < 2; ++qs) {
    const float inv = l_run[qs] > 0.f ? 1.f / l_run[qs] : 0.f;
#pragma unroll
    for (int ds = 0; ds < 4; ++ds) {
      short4 t4;
      t4.x = f2bf(o[qs][ds][0] * inv);
      t4.y = f2bf(o[qs][ds][1] * inv);
      t4.z = f2bf(o[qs][ds][2] * inv);
      t4.w = f2bf(o[qs][ds][3] * inv);
      *reinterpret_cast<short4*>(
          &merged[(rowbase + qrow[qs]) * 512 + head * 64 + ds * 16 + lg * 4]) = t4;
    }
  }
}

// ---------------- launch ----------------
extern "C" void kernel_launch(void* const* d_in, const int* in_sizes, int n_in,
                              void* d_out, int out_size, void* d_ws, size_t ws_size,
                              hipStream_t stream) {
  const float* X        = (const float*)d_in[0];
  const float* STE      = (const float*)d_in[1];
  const int*   geo_mask = (const int*)d_in[2];
  const int*   sem_mask = (const int*)d_in[3];
  const float* PK       = (const float*)d_in[4];
  const float* Wq       = (const float*)d_in[5];
  const float* bq       = (const float*)d_in[6];
  const float* Wk       = (const float*)d_in[7];
  const float* bk       = (const float*)d_in[8];
  const float* Wv       = (const float*)d_in[9];
  const float* bv       = (const float*)d_in[10];
  const float* Wo       = (const float*)d_in[11];
  const float* bo       = (const float*)d_in[12];
  const float* Wsc      = (const float*)d_in[13];
  const float* Wwq      = (const float*)d_in[14];
  const float* Wpm      = (const float*)d_in[15];
  const float* Wpv      = (const float*)d_in[16];
  float* out = (float*)d_out;

  char* wsb = (char*)d_ws;
  short* Abf     = (short*)(wsb);                    // 24576x1024 bf16
  short* mergedb = (short*)(wsb);                    // aliases Abf (dead after QKV)
  short* Cm      = (short*)(wsb + 50331648);         // 24576x1024 bf16: q|k
  short* vT      = (short*)(wsb + 100663296);        // 512x24576 bf16
  short* Wt3     = (short*)(wsb + 125829120);        // 1536x1024 bf16
  short* Wot     = (short*)(wsb + 128974848);        // 512x512 bf16
  float* bqkv    = (float*)(wsb + 129499136);        // 1536 f32
  float* scalar  = (float*)(wsb + 129505280);        // 24576 f32
  float* mem     = (float*)(wsb + 129603584);
  float* val     = (float*)(wsb + 129619968);
  u64*   gbits   = (u64*)  (wsb + 129636352);
  u64*   sbits   = (u64*)  (wsb + 129669120);

  // all prep in one launch (cast+scalar | masks | tiled W transpose | bias | mem/val)
  prep_all<<<dim3(8662), dim3(256), 0, stream>>>(
      X, STE, geo_mask, sem_mask, PK, Wq, bq, Wk, bk, Wv, bv, Wo, Wsc, Wpm, Wpv,
      Abf, Wt3, Wot, bqkv, scalar, mem, val, gbits, sbits);

  // merged QKV GEMM: M=24576, K=1024, N=1536 (writes Cm q|k + vT transposed)
  gemm128<1, 12><<<dim3(2304), dim3(256), 0, stream>>>(
      Abf, 1024, Wt3, 1024, bqkv, Cm, vT, nullptr);

  // DFT branch adds into q channels [0,256)
  dft2<<<dim3(Mrows / 32), dim3(256), 0, stream>>>(scalar, Wwq, mem, val, Cm);

  // flash attention (fixed-reference softmax, no max pass)
  attn5<<<dim3(1536), dim3(256), 0, stream>>>(Cm, vT, gbits, sbits, mergedb);

  // output FC: M=24576, K=512, N=512, f32 out
  gemm128<0, 4><<<dim3(768), dim3(256), 0, stream>>>(
      mergedb, 512, Wot, 512, bo, nullptr, nullptr, out);
}